// Round 1
// baseline (9142.127 us; speedup 1.0000x reference)
//
#include <hip/hip_runtime.h>

// ---------------- types / helpers ----------------
typedef short bhalf8 __attribute__((ext_vector_type(8)));   // 8 bf16 in 4 VGPRs
typedef float f32x4  __attribute__((ext_vector_type(4)));

__device__ __forceinline__ unsigned short f2bf(float f) {
    unsigned int u = __builtin_bit_cast(unsigned int, f);
    u = (u + 0x7fffu + ((u >> 16) & 1u)) >> 16;   // RNE
    return (unsigned short)u;
}
__device__ __forceinline__ float bf2f(unsigned short h) {
    unsigned int u = ((unsigned int)h) << 16;
    return __builtin_bit_cast(float, u);
}

#define SEQ   512
#define BATCH 64
#define HID   1024
#define EMBD  1024
#define VOCAB 32000
#define N3H   3072

// ---------------- fp32 -> bf16 convert (4 elems/thread) ----------------
__global__ void k_cvt4(const float4* __restrict__ in, ushort4* __restrict__ out, int n4) {
    int i = blockIdx.x * blockDim.x + threadIdx.x;
    if (i < n4) {
        float4 v = in[i];
        ushort4 o;
        o.x = f2bf(v.x); o.y = f2bf(v.y); o.z = f2bf(v.z); o.w = f2bf(v.w);
        out[i] = o;
    }
}

// ---------------- W_hh convert + reorder ----------------
// original row j_orig = g*1024 + j  (g = gate r/z/n, j = hidden unit)
// new row = G*48 + g*16 + u   where G = j>>4, u = j&15
__global__ void k_whh_reorder(const float* __restrict__ w, unsigned short* __restrict__ out) {
    int idx = blockIdx.x * 256 + threadIdx.x;     // 0 .. 3072*1024-1
    int k   = idx & 1023;
    int row = idx >> 10;
    int g   = row >> 10;        // 0..2
    int j   = row & 1023;       // unit
    int G   = j >> 4;
    int u   = j & 15;
    out[(size_t)(G * 48 + g * 16 + u) * 1024 + k] = f2bf(w[idx]);
}

// ---------------- gi GEMM: (32768 x 1024) gathered-A  @  W_ih^T -> bf16 ----------------
// block = 256 thr (4 waves). tile m64 x n64. wave = m16 x n64. no LDS (L2-fed).
__global__ __launch_bounds__(256)
void k_gi(const int* __restrict__ tok, const unsigned short* __restrict__ embb,
          const unsigned short* __restrict__ wih, unsigned short* __restrict__ gi) {
    int nb = blockIdx.x;            // 0..47
    int mb = blockIdx.y;            // 0..511
    int w    = threadIdx.x >> 6;
    int lane = threadIdx.x & 63;
    int q = lane >> 4, l = lane & 15;
    int m0 = mb * 64 + w * 16;
    int n0 = nb * 64;

    const unsigned short* arow = embb + (size_t)tok[m0 + l] * EMBD + q * 8;
    const unsigned short* b0 = wih + (size_t)(n0 + l) * EMBD + q * 8;
    const unsigned short* b1 = b0 + 16 * EMBD;
    const unsigned short* b2 = b0 + 32 * EMBD;
    const unsigned short* b3 = b0 + 48 * EMBD;

    f32x4 acc0 = {0.f, 0.f, 0.f, 0.f}, acc1 = acc0, acc2 = acc0, acc3 = acc0;

#pragma unroll 4
    for (int kk = 0; kk < 32; ++kk) {
        int ko = kk * 32;
        bhalf8 a = *(const bhalf8*)(arow + ko);
        acc0 = __builtin_amdgcn_mfma_f32_16x16x32_bf16(a, *(const bhalf8*)(b0 + ko), acc0, 0, 0, 0);
        acc1 = __builtin_amdgcn_mfma_f32_16x16x32_bf16(a, *(const bhalf8*)(b1 + ko), acc1, 0, 0, 0);
        acc2 = __builtin_amdgcn_mfma_f32_16x16x32_bf16(a, *(const bhalf8*)(b2 + ko), acc2, 0, 0, 0);
        acc3 = __builtin_amdgcn_mfma_f32_16x16x32_bf16(a, *(const bhalf8*)(b3 + ko), acc3, 0, 0, 0);
    }
    // C/D layout: row(m) = q*4+reg, col(n) = l
#pragma unroll
    for (int r = 0; r < 4; ++r) {
        size_t mrow = (size_t)(m0 + q * 4 + r) * N3H;
        gi[mrow + n0 +  0 + l] = f2bf(acc0[r]);
        gi[mrow + n0 + 16 + l] = f2bf(acc1[r]);
        gi[mrow + n0 + 32 + l] = f2bf(acc2[r]);
        gi[mrow + n0 + 48 + l] = f2bf(acc3[r]);
    }
}

// ---------------- fused recurrent step ----------------
// grid = 128 blocks (64 unit-groups x 2 batch-halves), block = 128 thr (2 waves, m16 each)
// wave computes gh for its 16 batches x (16 units x 3 gates) via 3 MFMA accs, then gates.
__global__ __launch_bounds__(128)
void k_step(const unsigned short* __restrict__ hcur,   // bf16 [64][1024], A-side
            unsigned short* __restrict__ hnext,        // bf16 [64][1024]
            const unsigned short* __restrict__ whh,    // reordered bf16
            const unsigned short* __restrict__ gi_t,   // bf16 [64][3072]
            const float* __restrict__ bih, const float* __restrict__ bhh,
            const float* __restrict__ hprev_f,         // fp32 [64][1024]
            float* __restrict__ out_t) {               // fp32 [64][1024]
    int G  = blockIdx.x >> 1;        // unit group 0..63
    int mh = blockIdx.x & 1;
    int w    = threadIdx.x >> 6;
    int lane = threadIdx.x & 63;
    int q = lane >> 4, l = lane & 15;
    int m0 = mh * 32 + w * 16;

    const unsigned short* arow = hcur + (size_t)(m0 + l) * HID + q * 8;
    const unsigned short* br = whh + (size_t)(G * 48 + l) * HID + q * 8;
    const unsigned short* bz = br + 16 * HID;
    const unsigned short* bn = br + 32 * HID;

    f32x4 ar = {0.f, 0.f, 0.f, 0.f}, az = ar, an = ar;

#pragma unroll 4
    for (int kk = 0; kk < 32; ++kk) {
        int ko = kk * 32;
        bhalf8 a = *(const bhalf8*)(arow + ko);
        ar = __builtin_amdgcn_mfma_f32_16x16x32_bf16(a, *(const bhalf8*)(br + ko), ar, 0, 0, 0);
        az = __builtin_amdgcn_mfma_f32_16x16x32_bf16(a, *(const bhalf8*)(bz + ko), az, 0, 0, 0);
        an = __builtin_amdgcn_mfma_f32_16x16x32_bf16(a, *(const bhalf8*)(bn + ko), an, 0, 0, 0);
    }

    int unit = G * 16 + l;
    float bir = bih[unit], biz = bih[1024 + unit], bin = bih[2048 + unit];
    float bhr = bhh[unit], bhz = bhh[1024 + unit], bhn = bhh[2048 + unit];

#pragma unroll
    for (int r = 0; r < 4; ++r) {
        int b = m0 + q * 4 + r;
        const unsigned short* g = gi_t + (size_t)b * N3H;
        float i_r = bf2f(g[unit])        + bir;
        float i_z = bf2f(g[1024 + unit]) + biz;
        float i_n = bf2f(g[2048 + unit]) + bin;
        float rr = 1.f / (1.f + __expf(-(i_r + ar[r] + bhr)));
        float zz = 1.f / (1.f + __expf(-(i_z + az[r] + bhz)));
        float nn = tanhf(i_n + rr * (an[r] + bhn));
        float hp = hprev_f[(size_t)b * HID + unit];
        float hv = (1.f - zz) * nn + zz * hp;
        out_t[(size_t)b * HID + unit] = hv;
        hnext[(size_t)b * HID + unit] = f2bf(hv);
    }
}

// ---------------- launch ----------------
extern "C" void kernel_launch(void* const* d_in, const int* in_sizes, int n_in,
                              void* d_out, int out_size, void* d_ws, size_t ws_size,
                              hipStream_t stream) {
    const int*   input  = (const int*)  d_in[0];
    const float* hidden = (const float*)d_in[2];
    const float* emb    = (const float*)d_in[3];
    const float* W_ih   = (const float*)d_in[4];
    const float* W_hh   = (const float*)d_in[5];
    const float* b_ih   = (const float*)d_in[6];
    const float* b_hh   = (const float*)d_in[7];
    float* out = (float*)d_out;

    // workspace layout (bytes, all 256-aligned)
    const size_t EMB_BF = 0;                                  // 32000*1024*2 = 65,536,000
    const size_t WIH_BF = EMB_BF + (size_t)VOCAB * EMBD * 2;  // + 6,291,456
    const size_t WHH_BF = WIH_BF + (size_t)N3H * EMBD * 2;
    const size_t GI_OFF = WHH_BF + (size_t)N3H * HID * 2;     // + 201,326,592
    const size_t H_OFF  = GI_OFF + (size_t)SEQ * BATCH * N3H * 2;
    const size_t NEED   = H_OFF + 2u * BATCH * HID * 2;
    if (ws_size < NEED) return;   // workspace too small -> will fail validation loudly

    char* ws = (char*)d_ws;
    unsigned short* embb = (unsigned short*)(ws + EMB_BF);
    unsigned short* wihb = (unsigned short*)(ws + WIH_BF);
    unsigned short* whhb = (unsigned short*)(ws + WHH_BF);
    unsigned short* gib  = (unsigned short*)(ws + GI_OFF);
    unsigned short* hbuf = (unsigned short*)(ws + H_OFF);

    // converts
    {
        int n4 = VOCAB * EMBD / 4;
        k_cvt4<<<(n4 + 255) / 256, 256, 0, stream>>>((const float4*)emb, (ushort4*)embb, n4);
    }
    {
        int n4 = N3H * EMBD / 4;
        k_cvt4<<<(n4 + 255) / 256, 256, 0, stream>>>((const float4*)W_ih, (ushort4*)wihb, n4);
    }
    k_whh_reorder<<<N3H * HID / 256, 256, 0, stream>>>(W_hh, whhb);
    {
        int n4 = BATCH * HID / 4;
        k_cvt4<<<(n4 + 255) / 256, 256, 0, stream>>>((const float4*)hidden, (ushort4*)hbuf, n4);
    }

    // input-side GEMM for all timesteps
    k_gi<<<dim3(48, 512), 256, 0, stream>>>(input, embb, wihb, gib);

    // recurrence
    for (int t = 0; t < SEQ; ++t) {
        const unsigned short* hcur = hbuf + (size_t)(t & 1) * BATCH * HID;
        unsigned short* hnext = hbuf + (size_t)((t + 1) & 1) * BATCH * HID;
        const float* hprev_f = (t == 0) ? hidden : (out + (size_t)(t - 1) * BATCH * HID);
        k_step<<<128, 128, 0, stream>>>(hcur, hnext, whhb,
                                        gib + (size_t)t * BATCH * N3H,
                                        b_ih, b_hh, hprev_f,
                                        out + (size_t)t * BATCH * HID);
    }
}